// Round 1
// baseline (614.349 us; speedup 1.0000x reference)
//
#include <hip/hip_runtime.h>
#include <math.h>

#define B_  4096
#define C_  1000
#define P_  10
#define D_  256
#define N_  10000
#define E_  160000

// ---------------- helpers ----------------
__device__ __forceinline__ float waveReduceSum(float v){
  #pragma unroll
  for (int o = 32; o > 0; o >>= 1) v += __shfl_xor(v, o);
  return v;
}

// ---------------- degree histogram ----------------
__global__ void k_deg_hist(const int* __restrict__ dst, int* __restrict__ deg){
  int e = blockIdx.x * 256 + threadIdx.x;
  if (e < E_) atomicAdd(&deg[dst[e]], 1);
}

// ---------------- exclusive scan over N=10000 (one block, 1024 thr) --------
__global__ void k_scan(const int* __restrict__ deg, int* __restrict__ off,
                       int* __restrict__ cursor, float* __restrict__ isq){
  __shared__ int sums[1024];
  int t = threadIdx.x;
  int base = t * 10;
  int loc[10];
  int run = 0;
  #pragma unroll
  for (int i = 0; i < 10; ++i){
    int idx = base + i;
    int v = (idx < N_) ? deg[idx] : 0;
    loc[i] = run; run += v;
  }
  sums[t] = run;
  __syncthreads();
  for (int o = 1; o < 1024; o <<= 1){
    int v = sums[t];
    int u = (t >= o) ? sums[t - o] : 0;
    __syncthreads();
    sums[t] = v + u;
    __syncthreads();
  }
  int prefix = (t == 0) ? 0 : sums[t - 1];
  #pragma unroll
  for (int i = 0; i < 10; ++i){
    int idx = base + i;
    if (idx < N_){
      int o = prefix + loc[i];
      off[idx] = o;
      cursor[idx] = o;
      // deg includes self-loop (+1); always >= 1 so where()/max() are no-ops
      isq[idx] = 1.0f / sqrtf((float)(deg[idx] + 1));
    }
  }
  if (t == 1023) off[N_] = sums[1023];
}

// ---------------- CSR scatter (edge -> slot) ----------------
__global__ void k_scatter(const int* __restrict__ src, const int* __restrict__ dst,
                          int* __restrict__ cursor, const float* __restrict__ isq,
                          int* __restrict__ csr_src, float* __restrict__ csr_norm){
  int e = blockIdx.x * 256 + threadIdx.x;
  if (e >= E_) return;
  int d = dst[e], s = src[e];
  int p = atomicAdd(&cursor[d], 1);
  csr_src[p]  = s;
  csr_norm[p] = isq[s] * isq[d];
}

// ---------------- fp32 GEMM: out[M,256] = A[M,256] @ W[256,256] ----------------
// 64x64 tile, 256 thr, 4x4 micro-tile, k-chunk 32, A staged k-major in LDS.
__global__ __launch_bounds__(256) void k_gemm_nn(const float* __restrict__ A,
                                                 const float* __restrict__ W,
                                                 float* __restrict__ out, int M){
  __shared__ float As[32 * 64];
  __shared__ float Ws[32 * 64];
  int tid = threadIdx.x;
  int ty = tid >> 4, tx = tid & 15;
  int rb = blockIdx.x * 64;
  int cb = blockIdx.y * 64;
  float acc[4][4] = {};
  for (int kc = 0; kc < 256; kc += 32){
    #pragma unroll
    for (int j = 0; j < 2; ++j){
      int f = tid + 256 * j;            // 0..511 float4s of A tile (64 rows x 8 f4)
      int row = f >> 3, kq = f & 7;
      float4 v = make_float4(0.f, 0.f, 0.f, 0.f);
      int gr = rb + row;
      if (gr < M) v = *(const float4*)(A + (size_t)gr * 256 + kc + kq * 4);
      As[(kq * 4 + 0) * 64 + row] = v.x;
      As[(kq * 4 + 1) * 64 + row] = v.y;
      As[(kq * 4 + 2) * 64 + row] = v.z;
      As[(kq * 4 + 3) * 64 + row] = v.w;
    }
    #pragma unroll
    for (int j = 0; j < 2; ++j){
      int f = tid + 256 * j;            // 32 rows x 16 f4
      int r = f >> 4, cq = f & 15;
      float4 v = *(const float4*)(W + (size_t)(kc + r) * 256 + cb + cq * 4);
      *(float4*)(Ws + r * 64 + cq * 4) = v;
    }
    __syncthreads();
    #pragma unroll 8
    for (int k = 0; k < 32; ++k){
      float4 a = *(const float4*)(As + k * 64 + ty * 4);
      float4 b = *(const float4*)(Ws + k * 64 + tx * 4);
      float av[4] = {a.x, a.y, a.z, a.w};
      float bv[4] = {b.x, b.y, b.z, b.w};
      #pragma unroll
      for (int r = 0; r < 4; ++r)
        #pragma unroll
        for (int c = 0; c < 4; ++c)
          acc[r][c] += av[r] * bv[c];
    }
    __syncthreads();
  }
  #pragma unroll
  for (int r = 0; r < 4; ++r){
    int gr = rb + ty * 4 + r;
    if (gr < M){
      float4 v = make_float4(acc[r][0], acc[r][1], acc[r][2], acc[r][3]);
      *(float4*)(out + (size_t)gr * 256 + cb + tx * 4) = v;
    }
  }
}

// ---------------- GCN aggregation + bias + relu ----------------
__global__ void k_agg_relu(const float* __restrict__ XW, const int* __restrict__ off,
                           const int* __restrict__ csr_src, const float* __restrict__ csr_norm,
                           const float* __restrict__ isq, const float* __restrict__ bias,
                           float* __restrict__ out){
  int n = blockIdx.x, d = threadIdx.x;
  float is = isq[n];
  float acc = is * is * XW[(size_t)n * 256 + d];   // self-loop
  int e0 = off[n], e1 = off[n + 1];
  for (int i = e0; i < e1; ++i){
    int s = csr_src[i];
    float nm = csr_norm[i];
    acc += nm * XW[(size_t)s * 256 + d];
  }
  out[(size_t)n * 256 + d] = fmaxf(acc + bias[d], 0.f);
}

// ---------------- row L2 normalize (supports in == out) ----------------
__global__ void k_norm_rows(const float* in, float* outp){
  int r = blockIdx.x, t = threadIdx.x;
  float v = in[(size_t)r * 256 + t];
  float ss = waveReduceSum(v * v);
  __shared__ float red[4];
  int w = t >> 6;
  if ((t & 63) == 0) red[w] = ss;
  __syncthreads();
  float tot = red[0] + red[1] + red[2] + red[3];
  float nrm = fmaxf(sqrtf(tot), 1e-12f);
  outp[(size_t)r * 256 + t] = v / nrm;
}

// ---------------- column sums of proto_norm (for dispersion) ----------------
__global__ void k_colsum(const float* __restrict__ PN, float* __restrict__ s){
  int d = threadIdx.x;
  int r0 = blockIdx.x * 250;
  float acc = 0.f;
  for (int r = r0; r < r0 + 250; ++r) acc += PN[(size_t)r * 256 + d];
  atomicAdd(&s[d], acc);
}

// ---------------- fused sim GEMM + per-class max/argmax over P=10 ----------------
// block: 128 A-rows x 8 classes (80 proto rows); thread: 4 rows x 10 protos.
__global__ __launch_bounds__(256) void k_sim_max(const float* __restrict__ HN,
                                                 const float* __restrict__ PN,
                                                 float* __restrict__ out,
                                                 unsigned char* __restrict__ idxb){
  __shared__ float As[32 * 128];   // k-major [k][row]
  __shared__ float Bs[32 * 96];    // k-major [k][class*12 + p] (12-pad: bank-perfect)
  int tid = threadIdx.x;
  int ty = tid >> 3;     // 0..31 -> 4 rows each
  int tx = tid & 7;      // 0..7  -> class within block
  int rb = blockIdx.y * 128;
  int cbase = blockIdx.x * 8;
  float acc[4][10];
  #pragma unroll
  for (int r = 0; r < 4; ++r)
    #pragma unroll
    for (int p = 0; p < 10; ++p) acc[r][p] = 0.f;

  for (int kc = 0; kc < 256; kc += 32){
    #pragma unroll
    for (int j = 0; j < 4; ++j){
      int f = tid + 256 * j;          // 1024 f4s: 128 rows x 8
      int row = f >> 3, kq = f & 7;
      float4 v = *(const float4*)(HN + (size_t)(rb + row) * 256 + kc + kq * 4);
      As[(kq * 4 + 0) * 128 + row] = v.x;
      As[(kq * 4 + 1) * 128 + row] = v.y;
      As[(kq * 4 + 2) * 128 + row] = v.z;
      As[(kq * 4 + 3) * 128 + row] = v.w;
    }
    for (int f = tid; f < 640; f += 256){  // 80 proto rows x 8 f4
      int row = f >> 3, kq = f & 7;
      float4 v = *(const float4*)(PN + (size_t)(blockIdx.x * 80 + row) * 256 + kc + kq * 4);
      int cls = row / 10;
      int col = cls * 12 + (row - cls * 10);
      Bs[(kq * 4 + 0) * 96 + col] = v.x;
      Bs[(kq * 4 + 1) * 96 + col] = v.y;
      Bs[(kq * 4 + 2) * 96 + col] = v.z;
      Bs[(kq * 4 + 3) * 96 + col] = v.w;
    }
    __syncthreads();
    #pragma unroll 8
    for (int k = 0; k < 32; ++k){
      const float* bp = Bs + k * 96 + tx * 12;
      float4 a  = *(const float4*)(As + k * 128 + ty * 4);
      float4 b0 = *(const float4*)(bp);
      float4 b1 = *(const float4*)(bp + 4);
      float2 b2 = *(const float2*)(bp + 8);
      float av[4]  = {a.x, a.y, a.z, a.w};
      float bv[10] = {b0.x, b0.y, b0.z, b0.w, b1.x, b1.y, b1.z, b1.w, b2.x, b2.y};
      #pragma unroll
      for (int r = 0; r < 4; ++r)
        #pragma unroll
        for (int p = 0; p < 10; ++p)
          acc[r][p] += av[r] * bv[p];
    }
    __syncthreads();
  }
  int c = cbase + tx;
  #pragma unroll
  for (int r = 0; r < 4; ++r){
    int grow = rb + ty * 4 + r;
    // transform to sim space FIRST (matches reference rounding), then first-max argmax
    float m = 0.5f * (1.0f + acc[r][0]); int mi = 0;
    #pragma unroll
    for (int p = 1; p < 10; ++p){
      float v = 0.5f * (1.0f + acc[r][p]);
      if (v > m){ m = v; mi = p; }
    }
    out [(size_t)grow * 1000 + c] = m;
    idxb[(size_t)grow * 1000 + c] = (unsigned char)mi;
  }
}

// ---------------- per-sample pass: softmax CE + mask + usage ----------------
__global__ void k_row_pass(const float* __restrict__ out, const unsigned char* __restrict__ idxb,
                           const int* __restrict__ labels, int* __restrict__ cnt,
                           float* __restrict__ ce_sum, float* __restrict__ pos_usage,
                           float* __restrict__ neg_usage){
  int b = blockIdx.x * 4 + (threadIdx.x >> 6);
  int lane = threadIdx.x & 63;
  const float* row = out + (size_t)b * 1000;
  float m = -INFINITY, s = 0.f; int bi = 0x7fffffff;
  for (int c = lane; c < 1000; c += 64){
    float v = row[c];
    if (v > m){ s = s * expf(m - v) + 1.f; bi = c; m = v; }
    else       s += expf(v - m);
  }
  #pragma unroll
  for (int o = 32; o > 0; o >>= 1){
    float m2 = __shfl_xor(m, o);
    float s2 = __shfl_xor(s, o);
    int   b2 = __shfl_xor(bi, o);
    float M = fmaxf(m, m2);
    s = s * expf(m - M) + s2 * expf(m2 - M);
    if (m2 > m || (m2 == m && b2 < bi)) bi = b2;
    m = M;
  }
  if (lane == 0){
    int lab = labels[b];
    float true_score = row[lab];
    float per_ce = m + logf(s) - true_score;      // logsumexp - true
    bool mask = (true_score - m) > -0.1f;
    if (mask){ atomicAdd(cnt, 1); atomicAdd(ce_sum, per_ce); }
    int pi = idxb[(size_t)b * 1000 + lab];
    atomicAdd(&pos_usage[lab * P_ + pi], 1.f);
    if (bi != lab){
      int ni = idxb[(size_t)b * 1000 + bi];
      atomicAdd(&neg_usage[bi * P_ + ni], 1.f);
    }
  }
}

// ---------------- finalize loss ----------------
__global__ void k_finalize(const float* __restrict__ s, const int* __restrict__ cnt,
                           const float* __restrict__ ce_sum, float* __restrict__ loss_out){
  int t = threadIdx.x;
  float v = s[t];
  float ss = waveReduceSum(v * v);
  __shared__ float red[4];
  if ((t & 63) == 0) red[t >> 6] = ss;
  __syncthreads();
  if (t == 0){
    float tot = red[0] + red[1] + red[2] + red[3];
    float disp = -tot / 1.0e8f;                   // N*N = 1e8
    int c = *cnt;
    float total = (c == 0) ? 0.f
                : (*ce_sum / (float)(c < 1 ? 1 : c) + 0.1f * disp);
    *loss_out = total;
  }
}

// ---------------- launcher ----------------
extern "C" void kernel_launch(void* const* d_in, const int* in_sizes, int n_in,
                              void* d_out, int out_size, void* d_ws, size_t ws_size,
                              hipStream_t stream){
  const float* hidden = (const float*)d_in[0];
  const int*   labels = (const int*)  d_in[1];
  const int*   eidx   = (const int*)  d_in[2];
  const float* nodef  = (const float*)d_in[3];
  const float* w1     = (const float*)d_in[4];
  const float* b1     = (const float*)d_in[5];
  const float* w2     = (const float*)d_in[6];
  const float* b2     = (const float*)d_in[7];

  float* out       = (float*)d_out;
  float* loss_out  = out + (size_t)B_ * C_;
  float* pos_usage = loss_out + 1;
  float* neg_usage = pos_usage + N_;

  const int* srcp = eidx;
  const int* dstp = eidx + E_;

  char* base = (char*)d_ws;
  size_t off = 0;
  auto alloc = [&](size_t bytes) -> char* {
    char* p = base + off;
    off = (off + bytes + 255) & ~(size_t)255;
    return p;
  };
  // zero zone (one memset): deg_cnt, svec, cnt, ce_sum
  int*   deg_cnt = (int*)  alloc((size_t)N_ * 4);
  float* svec    = (float*)alloc(256 * 4);
  int*   cnt     = (int*)  alloc(4);
  float* ce_sum  = (float*)alloc(4);
  size_t zero_bytes = off;
  float* deg_isqrt = (float*)alloc((size_t)N_ * 4);
  int*   csr_off   = (int*)  alloc((size_t)(N_ + 1) * 4);
  int*   cursor    = (int*)  alloc((size_t)N_ * 4);
  int*   csr_src   = (int*)  alloc((size_t)E_ * 4);
  float* csr_norm  = (float*)alloc((size_t)E_ * 4);
  float* XW        = (float*)alloc((size_t)N_ * 256 * 4);
  float* X1        = (float*)alloc((size_t)N_ * 256 * 4);   // layer outputs; normalized in-place
  float* HN        = (float*)alloc((size_t)B_ * 256 * 4);
  unsigned char* idxb = (unsigned char*)alloc((size_t)B_ * C_);

  hipMemsetAsync(base, 0, zero_bytes, stream);
  hipMemsetAsync(loss_out, 0, (size_t)(1 + 2 * N_) * 4, stream);

  k_deg_hist<<<(E_ + 255) / 256, 256, 0, stream>>>(dstp, deg_cnt);
  k_scan<<<1, 1024, 0, stream>>>(deg_cnt, csr_off, cursor, deg_isqrt);
  k_scatter<<<(E_ + 255) / 256, 256, 0, stream>>>(srcp, dstp, cursor, deg_isqrt, csr_src, csr_norm);

  dim3 ggrid(157, 4);
  k_gemm_nn<<<ggrid, 256, 0, stream>>>(nodef, w1, XW, N_);
  k_agg_relu<<<N_, 256, 0, stream>>>(XW, csr_off, csr_src, csr_norm, deg_isqrt, b1, X1);
  k_gemm_nn<<<ggrid, 256, 0, stream>>>(X1, w2, XW, N_);
  k_agg_relu<<<N_, 256, 0, stream>>>(XW, csr_off, csr_src, csr_norm, deg_isqrt, b2, X1);

  k_norm_rows<<<N_, 256, 0, stream>>>(X1, X1);        // proto_norm in place
  k_norm_rows<<<B_, 256, 0, stream>>>(hidden, HN);    // hidden_norm
  k_colsum<<<40, 256, 0, stream>>>(X1, svec);

  dim3 sgrid(125, 32);
  k_sim_max<<<sgrid, 256, 0, stream>>>(HN, X1, out, idxb);

  k_row_pass<<<B_ / 4, 256, 0, stream>>>(out, idxb, labels, cnt, ce_sum, pos_usage, neg_usage);
  k_finalize<<<1, 256, 0, stream>>>(svec, cnt, ce_sum, loss_out);
}

// Round 2
// 581.322 us; speedup vs baseline: 1.0568x; 1.0568x over previous
//
#include <hip/hip_runtime.h>
#include <math.h>

#define B_  4096
#define C_  1000
#define P_  10
#define D_  256
#define N_  10000
#define E_  160000

// ---------------- helpers ----------------
__device__ __forceinline__ float waveReduceSum(float v){
  #pragma unroll
  for (int o = 32; o > 0; o >>= 1) v += __shfl_xor(v, o);
  return v;
}

// ---------------- degree histogram ----------------
__global__ void k_deg_hist(const int* __restrict__ dst, int* __restrict__ deg){
  int e = blockIdx.x * 256 + threadIdx.x;
  if (e < E_) atomicAdd(&deg[dst[e]], 1);
}

// ---------------- exclusive scan over N=10000 (one block, 1024 thr) --------
__global__ void k_scan(const int* __restrict__ deg, int* __restrict__ off,
                       int* __restrict__ cursor, float* __restrict__ isq){
  __shared__ int sums[1024];
  int t = threadIdx.x;
  int base = t * 10;
  int loc[10];
  int run = 0;
  #pragma unroll
  for (int i = 0; i < 10; ++i){
    int idx = base + i;
    int v = (idx < N_) ? deg[idx] : 0;
    loc[i] = run; run += v;
  }
  sums[t] = run;
  __syncthreads();
  for (int o = 1; o < 1024; o <<= 1){
    int v = sums[t];
    int u = (t >= o) ? sums[t - o] : 0;
    __syncthreads();
    sums[t] = v + u;
    __syncthreads();
  }
  int prefix = (t == 0) ? 0 : sums[t - 1];
  #pragma unroll
  for (int i = 0; i < 10; ++i){
    int idx = base + i;
    if (idx < N_){
      int o = prefix + loc[i];
      off[idx] = o;
      cursor[idx] = o;
      // deg includes self-loop (+1); always >= 1 so where()/max() are no-ops
      isq[idx] = 1.0f / sqrtf((float)(deg[idx] + 1));
    }
  }
  if (t == 1023) off[N_] = sums[1023];
}

// ---------------- CSR scatter (edge -> slot) ----------------
__global__ void k_scatter(const int* __restrict__ src, const int* __restrict__ dst,
                          int* __restrict__ cursor, const float* __restrict__ isq,
                          int* __restrict__ csr_src, float* __restrict__ csr_norm){
  int e = blockIdx.x * 256 + threadIdx.x;
  if (e >= E_) return;
  int d = dst[e], s = src[e];
  int p = atomicAdd(&cursor[d], 1);
  csr_src[p]  = s;
  csr_norm[p] = isq[s] * isq[d];
}

// ---------------- fp32 GEMM: out[M,256] = A[M,256] @ W[256,256] ----------------
// 64x64 tile, 256 thr, 4x4 micro-tile, k-chunk 32, A staged k-major in LDS.
__global__ __launch_bounds__(256) void k_gemm_nn(const float* __restrict__ A,
                                                 const float* __restrict__ W,
                                                 float* __restrict__ out, int M){
  __shared__ float As[32 * 64];
  __shared__ float Ws[32 * 64];
  int tid = threadIdx.x;
  int ty = tid >> 4, tx = tid & 15;
  int rb = blockIdx.x * 64;
  int cb = blockIdx.y * 64;
  float acc[4][4] = {};
  for (int kc = 0; kc < 256; kc += 32){
    #pragma unroll
    for (int j = 0; j < 2; ++j){
      int f = tid + 256 * j;            // 0..511 float4s of A tile (64 rows x 8 f4)
      int row = f >> 3, kq = f & 7;
      float4 v = make_float4(0.f, 0.f, 0.f, 0.f);
      int gr = rb + row;
      if (gr < M) v = *(const float4*)(A + (size_t)gr * 256 + kc + kq * 4);
      As[(kq * 4 + 0) * 64 + row] = v.x;
      As[(kq * 4 + 1) * 64 + row] = v.y;
      As[(kq * 4 + 2) * 64 + row] = v.z;
      As[(kq * 4 + 3) * 64 + row] = v.w;
    }
    #pragma unroll
    for (int j = 0; j < 2; ++j){
      int f = tid + 256 * j;            // 32 rows x 16 f4
      int r = f >> 4, cq = f & 15;
      float4 v = *(const float4*)(W + (size_t)(kc + r) * 256 + cb + cq * 4);
      *(float4*)(Ws + r * 64 + cq * 4) = v;
    }
    __syncthreads();
    #pragma unroll 8
    for (int k = 0; k < 32; ++k){
      float4 a = *(const float4*)(As + k * 64 + ty * 4);
      float4 b = *(const float4*)(Ws + k * 64 + tx * 4);
      float av[4] = {a.x, a.y, a.z, a.w};
      float bv[4] = {b.x, b.y, b.z, b.w};
      #pragma unroll
      for (int r = 0; r < 4; ++r)
        #pragma unroll
        for (int c = 0; c < 4; ++c)
          acc[r][c] += av[r] * bv[c];
    }
    __syncthreads();
  }
  #pragma unroll
  for (int r = 0; r < 4; ++r){
    int gr = rb + ty * 4 + r;
    if (gr < M){
      float4 v = make_float4(acc[r][0], acc[r][1], acc[r][2], acc[r][3]);
      *(float4*)(out + (size_t)gr * 256 + cb + tx * 4) = v;
    }
  }
}

// ---------------- GCN aggregation + bias + relu ----------------
__global__ void k_agg_relu(const float* __restrict__ XW, const int* __restrict__ off,
                           const int* __restrict__ csr_src, const float* __restrict__ csr_norm,
                           const float* __restrict__ isq, const float* __restrict__ bias,
                           float* __restrict__ out){
  int n = blockIdx.x, d = threadIdx.x;
  float is = isq[n];
  float acc = is * is * XW[(size_t)n * 256 + d];   // self-loop
  int e0 = off[n], e1 = off[n + 1];
  for (int i = e0; i < e1; ++i){
    int s = csr_src[i];
    float nm = csr_norm[i];
    acc += nm * XW[(size_t)s * 256 + d];
  }
  out[(size_t)n * 256 + d] = fmaxf(acc + bias[d], 0.f);
}

// ---------------- row L2 normalize (supports in == out) ----------------
__global__ void k_norm_rows(const float* in, float* outp){
  int r = blockIdx.x, t = threadIdx.x;
  float v = in[(size_t)r * 256 + t];
  float ss = waveReduceSum(v * v);
  __shared__ float red[4];
  int w = t >> 6;
  if ((t & 63) == 0) red[w] = ss;
  __syncthreads();
  float tot = red[0] + red[1] + red[2] + red[3];
  float nrm = fmaxf(sqrtf(tot), 1e-12f);
  outp[(size_t)r * 256 + t] = v / nrm;
}

// ---------------- column sums of proto_norm (for dispersion) ----------------
__global__ void k_colsum(const float* __restrict__ PN, float* __restrict__ s){
  int d = threadIdx.x;
  int r0 = blockIdx.x * 250;
  float acc = 0.f;
  for (int r = r0; r < r0 + 250; ++r) acc += PN[(size_t)r * 256 + d];
  atomicAdd(&s[d], acc);
}

// ---------------- fused sim GEMM + per-class max/argmax over P=10 ----------------
// block: 256 A-rows x 8 classes (80 proto rows); thread: 8 rows x 10 protos.
// LDS: As[k][256] (stride 256; staged per-own-row: write bank = tid%32, 2-way=free)
//      Bs[k][100] (stride 100 = 4 mod 32 -> k-rotated banks; 64 rows/wave staging)
__global__ __launch_bounds__(256, 3) void k_sim_max(const float* __restrict__ HN,
                                                    const float* __restrict__ PN,
                                                    float* __restrict__ out,
                                                    unsigned char* __restrict__ idxb){
  __shared__ float As[32 * 256];
  __shared__ float Bs[32 * 100];
  int tid = threadIdx.x;
  int ty = tid >> 3;     // 0..31 -> 8 rows each
  int tx = tid & 7;      // 0..7  -> class within block
  int rb = blockIdx.y * 256;
  int cbase = blockIdx.x * 8;
  float acc[8][10];
  #pragma unroll
  for (int r = 0; r < 8; ++r)
    #pragma unroll
    for (int p = 0; p < 10; ++p) acc[r][p] = 0.f;

  const float* Arow = HN + (size_t)(rb + tid) * 256;

  for (int kc = 0; kc < 256; kc += 32){
    // --- As: thread stages its OWN row's 32-k chunk (one 128B line, 8 f4s) ---
    #pragma unroll
    for (int j = 0; j < 8; ++j){
      float4 v = *(const float4*)(Arow + kc + j * 4);
      As[(j * 4 + 0) * 256 + tid] = v.x;
      As[(j * 4 + 1) * 256 + tid] = v.y;
      As[(j * 4 + 2) * 256 + tid] = v.z;
      As[(j * 4 + 3) * 256 + tid] = v.w;
    }
    // --- Bs: 80 proto rows x 8 f4s; 64 distinct rows per wave ---
    #pragma unroll
    for (int f = tid; f < 640; f += 256){
      int row = f % 80;
      int kq  = f / 80;
      float4 v = *(const float4*)(PN + (size_t)(blockIdx.x * 80 + row) * 256 + kc + kq * 4);
      int cls = row / 10;
      int col = cls * 12 + (row - cls * 10);
      Bs[(kq * 4 + 0) * 100 + col] = v.x;
      Bs[(kq * 4 + 1) * 100 + col] = v.y;
      Bs[(kq * 4 + 2) * 100 + col] = v.z;
      Bs[(kq * 4 + 3) * 100 + col] = v.w;
    }
    __syncthreads();
    #pragma unroll 4
    for (int k = 0; k < 32; ++k){
      const float* ap = As + k * 256 + ty * 8;
      float4 a0 = *(const float4*)(ap);
      float4 a1 = *(const float4*)(ap + 4);
      const float* bp = Bs + k * 100 + tx * 12;
      float4 b0 = *(const float4*)(bp);
      float4 b1 = *(const float4*)(bp + 4);
      float2 b2 = *(const float2*)(bp + 8);
      float av[8]  = {a0.x, a0.y, a0.z, a0.w, a1.x, a1.y, a1.z, a1.w};
      float bv[10] = {b0.x, b0.y, b0.z, b0.w, b1.x, b1.y, b1.z, b1.w, b2.x, b2.y};
      #pragma unroll
      for (int r = 0; r < 8; ++r)
        #pragma unroll
        for (int p = 0; p < 10; ++p)
          acc[r][p] += av[r] * bv[p];
    }
    __syncthreads();
  }
  int c = cbase + tx;
  #pragma unroll
  for (int r = 0; r < 8; ++r){
    int grow = rb + ty * 8 + r;
    // transform to sim space FIRST (matches reference rounding), then first-max argmax
    float m = 0.5f * (1.0f + acc[r][0]); int mi = 0;
    #pragma unroll
    for (int p = 1; p < 10; ++p){
      float v = 0.5f * (1.0f + acc[r][p]);
      if (v > m){ m = v; mi = p; }
    }
    out [(size_t)grow * 1000 + c] = m;
    idxb[(size_t)grow * 1000 + c] = (unsigned char)mi;
  }
}

// ---------------- per-sample pass: softmax CE + mask + usage ----------------
__global__ void k_row_pass(const float* __restrict__ out, const unsigned char* __restrict__ idxb,
                           const int* __restrict__ labels, int* __restrict__ cnt,
                           float* __restrict__ ce_sum, float* __restrict__ pos_usage,
                           float* __restrict__ neg_usage){
  int b = blockIdx.x * 4 + (threadIdx.x >> 6);
  int lane = threadIdx.x & 63;
  const float* row = out + (size_t)b * 1000;
  float m = -INFINITY, s = 0.f; int bi = 0x7fffffff;
  for (int c = lane; c < 1000; c += 64){
    float v = row[c];
    if (v > m){ s = s * expf(m - v) + 1.f; bi = c; m = v; }
    else       s += expf(v - m);
  }
  #pragma unroll
  for (int o = 32; o > 0; o >>= 1){
    float m2 = __shfl_xor(m, o);
    float s2 = __shfl_xor(s, o);
    int   b2 = __shfl_xor(bi, o);
    float M = fmaxf(m, m2);
    s = s * expf(m - M) + s2 * expf(m2 - M);
    if (m2 > m || (m2 == m && b2 < bi)) bi = b2;
    m = M;
  }
  if (lane == 0){
    int lab = labels[b];
    float true_score = row[lab];
    float per_ce = m + logf(s) - true_score;      // logsumexp - true
    bool mask = (true_score - m) > -0.1f;
    if (mask){ atomicAdd(cnt, 1); atomicAdd(ce_sum, per_ce); }
    int pi = idxb[(size_t)b * 1000 + lab];
    atomicAdd(&pos_usage[lab * P_ + pi], 1.f);
    if (bi != lab){
      int ni = idxb[(size_t)b * 1000 + bi];
      atomicAdd(&neg_usage[bi * P_ + ni], 1.f);
    }
  }
}

// ---------------- finalize loss ----------------
__global__ void k_finalize(const float* __restrict__ s, const int* __restrict__ cnt,
                           const float* __restrict__ ce_sum, float* __restrict__ loss_out){
  int t = threadIdx.x;
  float v = s[t];
  float ss = waveReduceSum(v * v);
  __shared__ float red[4];
  if ((t & 63) == 0) red[t >> 6] = ss;
  __syncthreads();
  if (t == 0){
    float tot = red[0] + red[1] + red[2] + red[3];
    float disp = -tot / 1.0e8f;                   // N*N = 1e8
    int c = *cnt;
    float total = (c == 0) ? 0.f
                : (*ce_sum / (float)(c < 1 ? 1 : c) + 0.1f * disp);
    *loss_out = total;
  }
}

// ---------------- launcher ----------------
extern "C" void kernel_launch(void* const* d_in, const int* in_sizes, int n_in,
                              void* d_out, int out_size, void* d_ws, size_t ws_size,
                              hipStream_t stream){
  const float* hidden = (const float*)d_in[0];
  const int*   labels = (const int*)  d_in[1];
  const int*   eidx   = (const int*)  d_in[2];
  const float* nodef  = (const float*)d_in[3];
  const float* w1     = (const float*)d_in[4];
  const float* b1     = (const float*)d_in[5];
  const float* w2     = (const float*)d_in[6];
  const float* b2     = (const float*)d_in[7];

  float* out       = (float*)d_out;
  float* loss_out  = out + (size_t)B_ * C_;
  float* pos_usage = loss_out + 1;
  float* neg_usage = pos_usage + N_;

  const int* srcp = eidx;
  const int* dstp = eidx + E_;

  char* base = (char*)d_ws;
  size_t off = 0;
  auto alloc = [&](size_t bytes) -> char* {
    char* p = base + off;
    off = (off + bytes + 255) & ~(size_t)255;
    return p;
  };
  // zero zone (one memset): deg_cnt, svec, cnt, ce_sum
  int*   deg_cnt = (int*)  alloc((size_t)N_ * 4);
  float* svec    = (float*)alloc(256 * 4);
  int*   cnt     = (int*)  alloc(4);
  float* ce_sum  = (float*)alloc(4);
  size_t zero_bytes = off;
  float* deg_isqrt = (float*)alloc((size_t)N_ * 4);
  int*   csr_off   = (int*)  alloc((size_t)(N_ + 1) * 4);
  int*   cursor    = (int*)  alloc((size_t)N_ * 4);
  int*   csr_src   = (int*)  alloc((size_t)E_ * 4);
  float* csr_norm  = (float*)alloc((size_t)E_ * 4);
  float* XW        = (float*)alloc((size_t)N_ * 256 * 4);
  float* X1        = (float*)alloc((size_t)N_ * 256 * 4);   // layer outputs; normalized in-place
  float* HN        = (float*)alloc((size_t)B_ * 256 * 4);
  unsigned char* idxb = (unsigned char*)alloc((size_t)B_ * C_);

  hipMemsetAsync(base, 0, zero_bytes, stream);
  hipMemsetAsync(loss_out, 0, (size_t)(1 + 2 * N_) * 4, stream);

  k_deg_hist<<<(E_ + 255) / 256, 256, 0, stream>>>(dstp, deg_cnt);
  k_scan<<<1, 1024, 0, stream>>>(deg_cnt, csr_off, cursor, deg_isqrt);
  k_scatter<<<(E_ + 255) / 256, 256, 0, stream>>>(srcp, dstp, cursor, deg_isqrt, csr_src, csr_norm);

  dim3 ggrid(157, 4);
  k_gemm_nn<<<ggrid, 256, 0, stream>>>(nodef, w1, XW, N_);
  k_agg_relu<<<N_, 256, 0, stream>>>(XW, csr_off, csr_src, csr_norm, deg_isqrt, b1, X1);
  k_gemm_nn<<<ggrid, 256, 0, stream>>>(X1, w2, XW, N_);
  k_agg_relu<<<N_, 256, 0, stream>>>(XW, csr_off, csr_src, csr_norm, deg_isqrt, b2, X1);

  k_norm_rows<<<N_, 256, 0, stream>>>(X1, X1);        // proto_norm in place
  k_norm_rows<<<B_, 256, 0, stream>>>(hidden, HN);    // hidden_norm
  k_colsum<<<40, 256, 0, stream>>>(X1, svec);

  dim3 sgrid(125, 16);
  k_sim_max<<<sgrid, 256, 0, stream>>>(HN, X1, out, idxb);

  k_row_pass<<<B_ / 4, 256, 0, stream>>>(out, idxb, labels, cnt, ce_sum, pos_usage, neg_usage);
  k_finalize<<<1, 256, 0, stream>>>(svec, cnt, ce_sum, loss_out);
}

// Round 3
// 439.286 us; speedup vs baseline: 1.3985x; 1.3233x over previous
//
#include <hip/hip_runtime.h>
#include <math.h>

#define B_  4096
#define C_  1000
#define P_  10
#define D_  256
#define N_  10000
#define E_  160000

typedef __attribute__((ext_vector_type(8))) short short8;
typedef __attribute__((ext_vector_type(4))) float floatx4;

// ---------------- helpers ----------------
__device__ __forceinline__ float waveReduceSum(float v){
  #pragma unroll
  for (int o = 32; o > 0; o >>= 1) v += __shfl_xor(v, o);
  return v;
}
__device__ __forceinline__ unsigned short f2bf(float f){
  unsigned int u = __float_as_uint(f);
  unsigned int r = (u + 0x7FFFu + ((u >> 16) & 1u)) >> 16;
  return (unsigned short)r;
}
__device__ __forceinline__ float bf2f(unsigned short b){
  return __uint_as_float(((unsigned int)b) << 16);
}

// ---------------- degree histogram ----------------
__global__ void k_deg_hist(const int* __restrict__ dst, int* __restrict__ deg){
  int e = blockIdx.x * 256 + threadIdx.x;
  if (e < E_) atomicAdd(&deg[dst[e]], 1);
}

// ---------------- exclusive scan over N=10000 (one block, 1024 thr) --------
__global__ void k_scan(const int* __restrict__ deg, int* __restrict__ off,
                       int* __restrict__ cursor, float* __restrict__ isq){
  __shared__ int sums[1024];
  int t = threadIdx.x;
  int base = t * 10;
  int loc[10];
  int run = 0;
  #pragma unroll
  for (int i = 0; i < 10; ++i){
    int idx = base + i;
    int v = (idx < N_) ? deg[idx] : 0;
    loc[i] = run; run += v;
  }
  sums[t] = run;
  __syncthreads();
  for (int o = 1; o < 1024; o <<= 1){
    int v = sums[t];
    int u = (t >= o) ? sums[t - o] : 0;
    __syncthreads();
    sums[t] = v + u;
    __syncthreads();
  }
  int prefix = (t == 0) ? 0 : sums[t - 1];
  #pragma unroll
  for (int i = 0; i < 10; ++i){
    int idx = base + i;
    if (idx < N_){
      int o = prefix + loc[i];
      off[idx] = o;
      cursor[idx] = o;
      isq[idx] = 1.0f / sqrtf((float)(deg[idx] + 1));
    }
  }
  if (t == 1023) off[N_] = sums[1023];
}

// ---------------- CSR scatter (edge -> slot) ----------------
__global__ void k_scatter(const int* __restrict__ src, const int* __restrict__ dst,
                          int* __restrict__ cursor, const float* __restrict__ isq,
                          int* __restrict__ csr_src, float* __restrict__ csr_norm){
  int e = blockIdx.x * 256 + threadIdx.x;
  if (e >= E_) return;
  int d = dst[e], s = src[e];
  int p = atomicAdd(&cursor[d], 1);
  csr_src[p]  = s;
  csr_norm[p] = isq[s] * isq[d];
}

// ---------------- fp32 GEMM: out[M,256] = A[M,256] @ W[256,256] ----------------
__global__ __launch_bounds__(256) void k_gemm_nn(const float* __restrict__ A,
                                                 const float* __restrict__ W,
                                                 float* __restrict__ out, int M){
  __shared__ float As[32 * 64];
  __shared__ float Ws[32 * 64];
  int tid = threadIdx.x;
  int ty = tid >> 4, tx = tid & 15;
  int rb = blockIdx.x * 64;
  int cb = blockIdx.y * 64;
  float acc[4][4] = {};
  for (int kc = 0; kc < 256; kc += 32){
    #pragma unroll
    for (int j = 0; j < 2; ++j){
      int f = tid + 256 * j;
      int row = f >> 3, kq = f & 7;
      float4 v = make_float4(0.f, 0.f, 0.f, 0.f);
      int gr = rb + row;
      if (gr < M) v = *(const float4*)(A + (size_t)gr * 256 + kc + kq * 4);
      As[(kq * 4 + 0) * 64 + row] = v.x;
      As[(kq * 4 + 1) * 64 + row] = v.y;
      As[(kq * 4 + 2) * 64 + row] = v.z;
      As[(kq * 4 + 3) * 64 + row] = v.w;
    }
    #pragma unroll
    for (int j = 0; j < 2; ++j){
      int f = tid + 256 * j;
      int r = f >> 4, cq = f & 15;
      float4 v = *(const float4*)(W + (size_t)(kc + r) * 256 + cb + cq * 4);
      *(float4*)(Ws + r * 64 + cq * 4) = v;
    }
    __syncthreads();
    #pragma unroll 8
    for (int k = 0; k < 32; ++k){
      float4 a = *(const float4*)(As + k * 64 + ty * 4);
      float4 b = *(const float4*)(Ws + k * 64 + tx * 4);
      float av[4] = {a.x, a.y, a.z, a.w};
      float bv[4] = {b.x, b.y, b.z, b.w};
      #pragma unroll
      for (int r = 0; r < 4; ++r)
        #pragma unroll
        for (int c = 0; c < 4; ++c)
          acc[r][c] += av[r] * bv[c];
    }
    __syncthreads();
  }
  #pragma unroll
  for (int r = 0; r < 4; ++r){
    int gr = rb + ty * 4 + r;
    if (gr < M){
      float4 v = make_float4(acc[r][0], acc[r][1], acc[r][2], acc[r][3]);
      *(float4*)(out + (size_t)gr * 256 + cb + tx * 4) = v;
    }
  }
}

// ---------------- GCN aggregation + bias + relu ----------------
__global__ void k_agg_relu(const float* __restrict__ XW, const int* __restrict__ off,
                           const int* __restrict__ csr_src, const float* __restrict__ csr_norm,
                           const float* __restrict__ isq, const float* __restrict__ bias,
                           float* __restrict__ out){
  int n = blockIdx.x, d = threadIdx.x;
  float is = isq[n];
  float acc = is * is * XW[(size_t)n * 256 + d];   // self-loop
  int e0 = off[n], e1 = off[n + 1];
  for (int i = e0; i < e1; ++i){
    int s = csr_src[i];
    float nm = csr_norm[i];
    acc += nm * XW[(size_t)s * 256 + d];
  }
  out[(size_t)n * 256 + d] = fmaxf(acc + bias[d], 0.f);
}

// ---------------- row L2 normalize -> split bf16 hi/lo ----------------
__global__ void k_norm_split(const float* __restrict__ in,
                             unsigned short* __restrict__ hi,
                             unsigned short* __restrict__ lo){
  int r = blockIdx.x, t = threadIdx.x;
  float v = in[(size_t)r * 256 + t];
  float ss = waveReduceSum(v * v);
  __shared__ float red[4];
  int w = t >> 6;
  if ((t & 63) == 0) red[w] = ss;
  __syncthreads();
  float tot = red[0] + red[1] + red[2] + red[3];
  float nrm = fmaxf(sqrtf(tot), 1e-12f);
  float x = v / nrm;
  unsigned short h = f2bf(x);
  unsigned short l = f2bf(x - bf2f(h));
  hi[(size_t)r * 256 + t] = h;
  lo[(size_t)r * 256 + t] = l;
}

// ---------------- column sums of proto_norm (hi+lo) ----------------
__global__ void k_colsum(const unsigned short* __restrict__ hi,
                         const unsigned short* __restrict__ lo,
                         float* __restrict__ s){
  int d = threadIdx.x;
  int r0 = blockIdx.x * 250;
  float acc = 0.f;
  for (int r = r0; r < r0 + 250; ++r)
    acc += bf2f(hi[(size_t)r * 256 + d]) + bf2f(lo[(size_t)r * 256 + d]);
  atomicAdd(&s[d], acc);
}

// ---------------- MFMA sim GEMM (3-term bf16 split) + per-class max ------------
// block: 256 A-rows x 80 protos (8 classes). 4 waves, each 64 rows x 80 protos
// = 4x5 tiles of 16x16x32_bf16. K=256 in 8 chunks of 32. LDS rows padded to
// 80 B (stride 40 ushorts) -> frag b128 reads & staging writes are 2-way (free).
__global__ __launch_bounds__(256, 3) void k_sim_max(
    const unsigned short* __restrict__ HNh, const unsigned short* __restrict__ HNl,
    const unsigned short* __restrict__ PNh, const unsigned short* __restrict__ PNl,
    float* __restrict__ out, unsigned char* __restrict__ idxb){
  __shared__ __align__(16) char smem[53760];
  unsigned short* As_h = (unsigned short*)smem;              // 256*40*2 = 20480
  unsigned short* As_l = (unsigned short*)(smem + 20480);    // 20480
  unsigned short* Bs_h = (unsigned short*)(smem + 40960);    // 80*40*2 = 6400
  unsigned short* Bs_l = (unsigned short*)(smem + 47360);    // 6400

  int tid  = threadIdx.x;
  int wid  = tid >> 6;
  int lane = tid & 63;
  int l15  = lane & 15;
  int lq   = lane >> 4;        // 0..3
  int rb   = blockIdx.y * 256;
  int cb80 = blockIdx.x * 80;

  floatx4 acc[4][5];
  #pragma unroll
  for (int mt = 0; mt < 4; ++mt)
    #pragma unroll
    for (int nt = 0; nt < 5; ++nt) acc[mt][nt] = (floatx4){0.f, 0.f, 0.f, 0.f};

  for (int kc = 0; kc < 256; kc += 32){
    // stage A hi (1024 16B chunks) then A lo
    #pragma unroll
    for (int j = 0; j < 4; ++j){
      int f = tid + 256 * j;
      int row = f >> 2, kq = f & 3;
      uint4 v = *(const uint4*)(HNh + (size_t)(rb + row) * 256 + kc + kq * 8);
      *(uint4*)(As_h + row * 40 + kq * 8) = v;
    }
    #pragma unroll
    for (int j = 0; j < 4; ++j){
      int f = tid + 256 * j;
      int row = f >> 2, kq = f & 3;
      uint4 v = *(const uint4*)(HNl + (size_t)(rb + row) * 256 + kc + kq * 8);
      *(uint4*)(As_l + row * 40 + kq * 8) = v;
    }
    // stage B: 320 chunks hi + 320 lo
    for (int f = tid; f < 640; f += 256){
      int dt = (f >= 320);
      int f2 = dt ? f - 320 : f;
      int row = f2 >> 2, kq = f2 & 3;
      const unsigned short* gp = (dt ? PNl : PNh) + (size_t)(cb80 + row) * 256 + kc + kq * 8;
      uint4 v = *(const uint4*)gp;
      unsigned short* lp = (dt ? Bs_l : Bs_h) + row * 40 + kq * 8;
      *(uint4*)lp = v;
    }
    __syncthreads();

    short8 ah[4], al[4];
    #pragma unroll
    for (int mt = 0; mt < 4; ++mt){
      int ro = (wid * 64 + mt * 16 + l15) * 40 + lq * 8;
      ah[mt] = *(const short8*)(As_h + ro);
      al[mt] = *(const short8*)(As_l + ro);
    }
    #pragma unroll
    for (int nt = 0; nt < 5; ++nt){
      int ro = (nt * 16 + l15) * 40 + lq * 8;
      short8 bh = *(const short8*)(Bs_h + ro);
      short8 bl = *(const short8*)(Bs_l + ro);
      #pragma unroll
      for (int mt = 0; mt < 4; ++mt){
        floatx4 c = acc[mt][nt];
        c = __builtin_amdgcn_mfma_f32_16x16x32_bf16(al[mt], bh, c, 0, 0, 0);
        c = __builtin_amdgcn_mfma_f32_16x16x32_bf16(ah[mt], bl, c, 0, 0, 0);
        c = __builtin_amdgcn_mfma_f32_16x16x32_bf16(ah[mt], bh, c, 0, 0, 0);
        acc[mt][nt] = c;
      }
    }
    __syncthreads();
  }

  // epilogue: two 32-row halves through LDS (reuses As region: 4*32*80*4 = 40960 B)
  float* red = (float*)smem;
  for (int h = 0; h < 2; ++h){
    __syncthreads();
    #pragma unroll
    for (int m2 = 0; m2 < 2; ++m2){
      int mt = h * 2 + m2;
      #pragma unroll
      for (int nt = 0; nt < 5; ++nt)
        #pragma unroll
        for (int r = 0; r < 4; ++r){
          int rowhalf = m2 * 16 + lq * 4 + r;
          red[wid * 2560 + rowhalf * 80 + nt * 16 + l15] = acc[mt][nt][r];
        }
    }
    __syncthreads();
    int w     = tid >> 6;
    int rloc  = (tid & 63) >> 1;
    int half4 = tid & 1;
    const float* basep = red + w * 2560 + rloc * 80 + half4 * 40;
    float vs[4]; int is[4];
    #pragma unroll
    for (int cc = 0; cc < 4; ++cc){
      float m = 0.5f * (1.0f + basep[cc * 10]); int mi = 0;
      #pragma unroll
      for (int p = 1; p < 10; ++p){
        float v = 0.5f * (1.0f + basep[cc * 10 + p]);
        if (v > m){ m = v; mi = p; }
      }
      vs[cc] = m; is[cc] = mi;
    }
    int grow = blockIdx.y * 256 + w * 64 + h * 32 + rloc;
    int gcol = blockIdx.x * 8 + half4 * 4;
    *(float4*)(out + (size_t)grow * 1000 + gcol) = make_float4(vs[0], vs[1], vs[2], vs[3]);
    uchar4 u4; u4.x = (unsigned char)is[0]; u4.y = (unsigned char)is[1];
    u4.z = (unsigned char)is[2]; u4.w = (unsigned char)is[3];
    *(uchar4*)(idxb + (size_t)grow * 1000 + gcol) = u4;
  }
}

// ---------------- per-sample pass: softmax CE + mask + usage ----------------
__global__ void k_row_pass(const float* __restrict__ out, const unsigned char* __restrict__ idxb,
                           const int* __restrict__ labels, int* __restrict__ cnt,
                           float* __restrict__ ce_sum, float* __restrict__ pos_usage,
                           float* __restrict__ neg_usage){
  int b = blockIdx.x * 4 + (threadIdx.x >> 6);
  int lane = threadIdx.x & 63;
  const float* row = out + (size_t)b * 1000;
  float m = -INFINITY, s = 0.f; int bi = 0x7fffffff;
  for (int c = lane; c < 1000; c += 64){
    float v = row[c];
    if (v > m){ s = s * expf(m - v) + 1.f; bi = c; m = v; }
    else       s += expf(v - m);
  }
  #pragma unroll
  for (int o = 32; o > 0; o >>= 1){
    float m2 = __shfl_xor(m, o);
    float s2 = __shfl_xor(s, o);
    int   b2 = __shfl_xor(bi, o);
    float M = fmaxf(m, m2);
    s = s * expf(m - M) + s2 * expf(m2 - M);
    if (m2 > m || (m2 == m && b2 < bi)) bi = b2;
    m = M;
  }
  if (lane == 0){
    int lab = labels[b];
    float true_score = row[lab];
    float per_ce = m + logf(s) - true_score;
    bool mask = (true_score - m) > -0.1f;
    if (mask){ atomicAdd(cnt, 1); atomicAdd(ce_sum, per_ce); }
    int pi = idxb[(size_t)b * 1000 + lab];
    atomicAdd(&pos_usage[lab * P_ + pi], 1.f);
    if (bi != lab){
      int ni = idxb[(size_t)b * 1000 + bi];
      atomicAdd(&neg_usage[bi * P_ + ni], 1.f);
    }
  }
}

// ---------------- finalize loss ----------------
__global__ void k_finalize(const float* __restrict__ s, const int* __restrict__ cnt,
                           const float* __restrict__ ce_sum, float* __restrict__ loss_out){
  int t = threadIdx.x;
  float v = s[t];
  float ss = waveReduceSum(v * v);
  __shared__ float red[4];
  if ((t & 63) == 0) red[t >> 6] = ss;
  __syncthreads();
  if (t == 0){
    float tot = red[0] + red[1] + red[2] + red[3];
    float disp = -tot / 1.0e8f;
    int c = *cnt;
    float total = (c == 0) ? 0.f
                : (*ce_sum / (float)(c < 1 ? 1 : c) + 0.1f * disp);
    *loss_out = total;
  }
}

// ---------------- launcher ----------------
extern "C" void kernel_launch(void* const* d_in, const int* in_sizes, int n_in,
                              void* d_out, int out_size, void* d_ws, size_t ws_size,
                              hipStream_t stream){
  const float* hidden = (const float*)d_in[0];
  const int*   labels = (const int*)  d_in[1];
  const int*   eidx   = (const int*)  d_in[2];
  const float* nodef  = (const float*)d_in[3];
  const float* w1     = (const float*)d_in[4];
  const float* b1     = (const float*)d_in[5];
  const float* w2     = (const float*)d_in[6];
  const float* b2     = (const float*)d_in[7];

  float* out       = (float*)d_out;
  float* loss_out  = out + (size_t)B_ * C_;
  float* pos_usage = loss_out + 1;
  float* neg_usage = pos_usage + N_;

  const int* srcp = eidx;
  const int* dstp = eidx + E_;

  char* base = (char*)d_ws;
  size_t off = 0;
  auto alloc = [&](size_t bytes) -> char* {
    char* p = base + off;
    off = (off + bytes + 255) & ~(size_t)255;
    return p;
  };
  int*   deg_cnt = (int*)  alloc((size_t)N_ * 4);
  float* svec    = (float*)alloc(256 * 4);
  int*   cnt     = (int*)  alloc(4);
  float* ce_sum  = (float*)alloc(4);
  size_t zero_bytes = off;
  float* deg_isqrt = (float*)alloc((size_t)N_ * 4);
  int*   csr_off   = (int*)  alloc((size_t)(N_ + 1) * 4);
  int*   cursor    = (int*)  alloc((size_t)N_ * 4);
  int*   csr_src   = (int*)  alloc((size_t)E_ * 4);
  float* csr_norm  = (float*)alloc((size_t)E_ * 4);
  float* XW        = (float*)alloc((size_t)N_ * 256 * 4);
  float* X1        = (float*)alloc((size_t)N_ * 256 * 4);
  unsigned short* HNh = (unsigned short*)alloc((size_t)B_ * 256 * 2);
  unsigned short* HNl = (unsigned short*)alloc((size_t)B_ * 256 * 2);
  unsigned char* idxb = (unsigned char*)alloc((size_t)B_ * C_);
  // PN hi/lo alias XW (free after layer-2 aggregation): 2 * 5.12 MB <= 10.24 MB
  unsigned short* PNh = (unsigned short*)XW;
  unsigned short* PNl = PNh + (size_t)N_ * 256;

  hipMemsetAsync(base, 0, zero_bytes, stream);
  hipMemsetAsync(loss_out, 0, (size_t)(1 + 2 * N_) * 4, stream);

  k_deg_hist<<<(E_ + 255) / 256, 256, 0, stream>>>(dstp, deg_cnt);
  k_scan<<<1, 1024, 0, stream>>>(deg_cnt, csr_off, cursor, deg_isqrt);
  k_scatter<<<(E_ + 255) / 256, 256, 0, stream>>>(srcp, dstp, cursor, deg_isqrt, csr_src, csr_norm);

  dim3 ggrid(157, 4);
  k_gemm_nn<<<ggrid, 256, 0, stream>>>(nodef, w1, XW, N_);
  k_agg_relu<<<N_, 256, 0, stream>>>(XW, csr_off, csr_src, csr_norm, deg_isqrt, b1, X1);
  k_gemm_nn<<<ggrid, 256, 0, stream>>>(X1, w2, XW, N_);
  k_agg_relu<<<N_, 256, 0, stream>>>(XW, csr_off, csr_src, csr_norm, deg_isqrt, b2, X1);
  // NOTE: from here XW is dead as fp32; reused as PNh/PNl

  k_norm_split<<<N_, 256, 0, stream>>>(X1, PNh, PNl);      // proto_norm -> bf16 hi/lo
  k_norm_split<<<B_, 256, 0, stream>>>(hidden, HNh, HNl);  // hidden_norm -> bf16 hi/lo
  k_colsum<<<40, 256, 0, stream>>>(PNh, PNl, svec);

  dim3 sgrid(125, 16);
  k_sim_max<<<sgrid, 256, 0, stream>>>(HNh, HNl, PNh, PNl, out, idxb);

  k_row_pass<<<B_ / 4, 256, 0, stream>>>(out, idxb, labels, cnt, ce_sum, pos_usage, neg_usage);
  k_finalize<<<1, 256, 0, stream>>>(svec, cnt, ce_sum, loss_out);
}